// Round 15
// baseline (36.420 us; speedup 1.0000x reference)
//
#include <hip/hip_runtime.h>

#define B_N 8192
#define K_CL 64
#define CAP 256
#define NPAIR 2016
#define INF_F 3.0e38f

// Single self-contained pair kernel (2016 blocks) + tiny reduce.
// Attribution lesson (R5/R10): total = single kernel + ~0.5us, so this
// structure is directly measurable. In-block gather is CHAIN-FREE:
// packed one-pass block scan (no LDS atomics, no ballot rounds), ~1
// conditional coord load per thread, hidden by 2016-block TLP.
// ws: hinges float[2016]

__global__ __launch_bounds__(256) void pair_kernel(
    const int* __restrict__ labels, const float2* __restrict__ coords,
    float* __restrict__ hinges) {
    int p = blockIdx.x;                    // 0..2015
    int ci = 0, rem = p;                   // decode p -> (ci<cj), wave-uniform
    while (rem >= K_CL - 1 - ci) { rem -= K_CL - 1 - ci; ci++; }
    int cj = ci + 1 + rem;
    int tid = threadIdx.x, lane = tid & 63, wave = tid >> 6;

    __shared__ float2 ipt[CAP], jpt[CAP];
    __shared__ int wsum[4];
    __shared__ float wred[4];

    // preload 32 labels/thread (coalesced int4, L2-hot across blocks)
    int4 lb[8];
#pragma unroll
    for (int k = 0; k < 8; ++k)
        lb[k] = reinterpret_cast<const int4*>(labels)[tid + k * 256];

    int cntI = 0, cntJ = 0;
#pragma unroll
    for (int k = 0; k < 8; ++k) {
        cntI += (lb[k].x==ci) + (lb[k].y==ci) + (lb[k].z==ci) + (lb[k].w==ci);
        cntJ += (lb[k].x==cj) + (lb[k].y==cj) + (lb[k].z==cj) + (lb[k].w==cj);
    }

    // ONE packed exclusive scan for both counters (I<<16 | J; sums <= 8192)
    int pack = (cntI << 16) | cntJ;
    int incl = pack;
#pragma unroll
    for (int d = 1; d < 64; d <<= 1) {
        int u = __shfl_up(incl, d, 64);
        if (lane >= d) incl += u;
    }
    if (lane == 63) wsum[wave] = incl;
    __syncthreads();
    int wbase = 0, tot = 0;
#pragma unroll
    for (int w = 0; w < 4; ++w) {
        wbase += (w < wave) ? wsum[w] : 0;
        tot += wsum[w];
    }
    int basep = wbase + incl - pack;       // exclusive packed prefix
    int posI = basep >> 16, posJ = basep & 0xffff;
    int nI = min(tot >> 16, CAP), nJ = min(tot & 0xffff, CAP);

    // ~1 conditional scattered 8B load/thread avg; TLP hides latency
#pragma unroll
    for (int k = 0; k < 8; ++k) {
        int v4 = tid + k * 256;
        int lab[4] = {lb[k].x, lb[k].y, lb[k].z, lb[k].w};
#pragma unroll
        for (int cc = 0; cc < 4; ++cc) {
            if (lab[cc] == ci) {
                if (posI < CAP) ipt[posI] = coords[4 * v4 + cc];
                posI++;
            } else if (lab[cc] == cj) {
                if (posJ < CAP) jpt[posJ] = coords[4 * v4 + cc];
                posJ++;
            }
        }
    }
    __syncthreads();

    // 2 threads per i-point, 4-accumulator unrolled j-half (proven R13)
    int half = (nJ + 1) >> 1;
    int j0 = (tid & 1) ? half : 0;
    int j1 = (tid & 1) ? nJ : half;
    float m0 = INF_F, m1 = INF_F, m2 = INF_F, m3 = INF_F;
    for (int i = tid >> 1; i < nI; i += 128) {
        float2 pi = ipt[i];
        int j = j0;
        for (; j + 3 < j1; j += 4) {
            float2 a = jpt[j], b = jpt[j+1], c = jpt[j+2], d = jpt[j+3];
            float dx0 = pi.x - a.x, dy0 = pi.y - a.y;
            float dx1 = pi.x - b.x, dy1 = pi.y - b.y;
            float dx2 = pi.x - c.x, dy2 = pi.y - c.y;
            float dx3 = pi.x - d.x, dy3 = pi.y - d.y;
            m0 = fminf(m0, dx0*dx0 + dy0*dy0);
            m1 = fminf(m1, dx1*dx1 + dy1*dy1);
            m2 = fminf(m2, dx2*dx2 + dy2*dy2);
            m3 = fminf(m3, dx3*dx3 + dy3*dy3);
        }
        for (; j < j1; ++j) {
            float dx = pi.x - jpt[j].x, dy = pi.y - jpt[j].y;
            m0 = fminf(m0, dx*dx + dy*dy);
        }
    }
    float myMin = fminf(fminf(m0, m1), fminf(m2, m3));

    for (int off = 32; off > 0; off >>= 1)
        myMin = fminf(myMin, __shfl_down(myMin, off, 64));
    if (lane == 0) wred[wave] = myMin;
    __syncthreads();
    if (tid == 0) {
        float m = fminf(fminf(wred[0], wred[1]), fminf(wred[2], wred[3]));
        float h = 1.0f - sqrtf(m);
        hinges[p] = h > 0.0f ? h : 0.0f;
    }
}

__global__ void reduce_hinge_kernel(const float* __restrict__ hinges,
                                    float* __restrict__ out) {
    int tid = threadIdx.x;
    float s = 0.0f;
    for (int p = tid; p < NPAIR; p += 256) s += hinges[p];
    for (int off = 32; off > 0; off >>= 1)
        s += __shfl_down(s, off, 64);
    __shared__ float wsum[4];
    int wave = tid >> 6, lane = tid & 63;
    if (lane == 0) wsum[wave] = s;
    __syncthreads();
    if (tid == 0)
        out[0] = (wsum[0] + wsum[1] + wsum[2] + wsum[3]) / (float)NPAIR;
}

extern "C" void kernel_launch(void* const* d_in, const int* in_sizes, int n_in,
                              void* d_out, int out_size, void* d_ws, size_t ws_size,
                              hipStream_t stream) {
    const int*    labels = (const int*)d_in[1];     // cluster_labels (int32)
    const float2* coords = (const float2*)d_in[2];  // manifold_coords [8192,2] f32
    float* out    = (float*)d_out;
    float* hinges = (float*)d_ws;

    pair_kernel<<<NPAIR, 256, 0, stream>>>(labels, coords, hinges);
    reduce_hinge_kernel<<<1, 256, 0, stream>>>(hinges, out);
}

// Round 16
// 29.510 us; speedup vs baseline: 1.2342x; 1.2342x over previous
//
#include <hip/hip_runtime.h>

#define B_N 8192
#define K_CL 64
#define CAP 256
#define NPAIR 2016
#define INF_F 3.0e38f

// R16 = byte-identical restore of R13, the best measured config (29.49us).
// Evidence: R6/R12/R13 (three different gathers) all land 29.5-30.2us ->
// common ~29us harness floor (graph replay + per-dispatch overhead +
// 268MB inter-replay poison-fill drain); our kernels' true cost ~3-8us.
// Rocprof per-dispatch durations carry ~39us collection overhead (a 256B
// memset "measured" 39.6us in R11) - do not trust them for attribution.
// Known-bad (measured): fp32 same-addr atomics +36us, fence+done-counter
// +54us, spin-flags +100us, cg grid.sync +228us, extra memset dispatch
// +14us, per-pair in-block label rescan +7..18us.
// ws: lists float2[64*256] | cnts int[64] | hinges float[64*64]

__global__ __launch_bounds__(256) void gather_kernel(
    const int* __restrict__ labels, const float* __restrict__ coords,
    float2* __restrict__ lists, int* __restrict__ cnts) {
    int c = blockIdx.x;
    int tid = threadIdx.x, lane = tid & 63, wave = tid >> 6;
    __shared__ int wsum[4];

    // upfront unconditional loads into registers (full memory-level parallelism)
    int4 lb[8];
    float4 cr[16];
    const int4*   l4 = reinterpret_cast<const int4*>(labels);
    const float4* c4 = reinterpret_cast<const float4*>(coords);
#pragma unroll
    for (int k = 0; k < 8; ++k) {
        int v4 = tid + k * 256;
        lb[k]       = l4[v4];
        cr[2*k]     = c4[2*v4];        // points 4*v4+0, 4*v4+1 (x,y,x,y)
        cr[2*k + 1] = c4[2*v4 + 1];    // points 4*v4+2, 4*v4+3
    }
    int mcnt = 0;
#pragma unroll
    for (int k = 0; k < 8; ++k)
        mcnt += (lb[k].x==c) + (lb[k].y==c) + (lb[k].z==c) + (lb[k].w==c);

    // block exclusive scan (wave shfl_up + 4-wave LDS combine)
    int incl = mcnt;
#pragma unroll
    for (int d = 1; d < 64; d <<= 1) {
        int u = __shfl_up(incl, d, 64);
        if (lane >= d) incl += u;
    }
    if (lane == 63) wsum[wave] = incl;
    __syncthreads();
    int wbase = 0;
#pragma unroll
    for (int w = 0; w < 4; ++w) wbase += (w < wave) ? wsum[w] : 0;
    int base = wbase + incl - mcnt;
    if (tid == 255) cnts[c] = min(base + mcnt, CAP);

    // write loop: registers + stores only, no loads in the conditional chain
    int pos = base;
#pragma unroll
    for (int k = 0; k < 8; ++k) {
        float2 p0 = make_float2(cr[2*k].x,     cr[2*k].y);
        float2 p1 = make_float2(cr[2*k].z,     cr[2*k].w);
        float2 p2 = make_float2(cr[2*k + 1].x, cr[2*k + 1].y);
        float2 p3 = make_float2(cr[2*k + 1].z, cr[2*k + 1].w);
        if (lb[k].x == c) { if (pos < CAP) lists[c*CAP + pos] = p0; pos++; }
        if (lb[k].y == c) { if (pos < CAP) lists[c*CAP + pos] = p1; pos++; }
        if (lb[k].z == c) { if (pos < CAP) lists[c*CAP + pos] = p2; pos++; }
        if (lb[k].w == c) { if (pos < CAP) lists[c*CAP + pos] = p3; pos++; }
    }
}

__global__ __launch_bounds__(256) void pair_min_kernel(
    const float2* __restrict__ lists, const int* __restrict__ cnts,
    float* __restrict__ hinges) {
    int ci = blockIdx.x, cj = blockIdx.y;
    if (ci >= cj) return;                 // uniform per block
    int nI = min(cnts[ci], CAP), nJ = min(cnts[cj], CAP);
    int tid = threadIdx.x;
    __shared__ float2 ipt[CAP], jpt[CAP];
    if (tid < nJ) jpt[tid] = lists[cj * CAP + tid];
    if (tid < nI) ipt[tid] = lists[ci * CAP + tid];
    __syncthreads();

    // 2 threads per i-point (all 256 threads active), 4-acc unrolled j-half
    int half = (nJ + 1) >> 1;
    int j0 = (tid & 1) ? half : 0;
    int j1 = (tid & 1) ? nJ : half;
    float m0 = INF_F, m1 = INF_F, m2 = INF_F, m3 = INF_F;
    for (int i = tid >> 1; i < nI; i += 128) {
        float2 pi = ipt[i];
        int j = j0;
        for (; j + 3 < j1; j += 4) {
            float2 a = jpt[j], b = jpt[j+1], c = jpt[j+2], d = jpt[j+3];
            float dx0 = pi.x - a.x, dy0 = pi.y - a.y;
            float dx1 = pi.x - b.x, dy1 = pi.y - b.y;
            float dx2 = pi.x - c.x, dy2 = pi.y - c.y;
            float dx3 = pi.x - d.x, dy3 = pi.y - d.y;
            m0 = fminf(m0, dx0*dx0 + dy0*dy0);
            m1 = fminf(m1, dx1*dx1 + dy1*dy1);
            m2 = fminf(m2, dx2*dx2 + dy2*dy2);
            m3 = fminf(m3, dx3*dx3 + dy3*dy3);
        }
        for (; j < j1; ++j) {
            float dx = pi.x - jpt[j].x, dy = pi.y - jpt[j].y;
            m0 = fminf(m0, dx*dx + dy*dy);
        }
    }
    float myMin = fminf(fminf(m0, m1), fminf(m2, m3));

    for (int off = 32; off > 0; off >>= 1)
        myMin = fminf(myMin, __shfl_down(myMin, off, 64));
    __shared__ float wmin[4];
    int wave = tid >> 6, lane = tid & 63;
    if (lane == 0) wmin[wave] = myMin;
    __syncthreads();
    if (tid == 0) {
        float m = fminf(fminf(wmin[0], wmin[1]), fminf(wmin[2], wmin[3]));
        float h = 1.0f - sqrtf(m);
        hinges[ci * K_CL + cj] = h > 0.0f ? h : 0.0f;
    }
}

__global__ void reduce_hinge_kernel(const float* __restrict__ hinges,
                                    float* __restrict__ out) {
    int tid = threadIdx.x;
    float s = 0.0f;
    for (int p = tid; p < K_CL * K_CL; p += 256) {
        int ci = p >> 6, cj = p & 63;
        if (ci < cj) s += hinges[p];
    }
    for (int off = 32; off > 0; off >>= 1)
        s += __shfl_down(s, off, 64);
    __shared__ float wsum[4];
    int wave = tid >> 6, lane = tid & 63;
    if (lane == 0) wsum[wave] = s;
    __syncthreads();
    if (tid == 0)
        out[0] = (wsum[0] + wsum[1] + wsum[2] + wsum[3]) / (float)NPAIR;
}

extern "C" void kernel_launch(void* const* d_in, const int* in_sizes, int n_in,
                              void* d_out, int out_size, void* d_ws, size_t ws_size,
                              hipStream_t stream) {
    const int*   labels = (const int*)d_in[1];     // cluster_labels (int32)
    const float* coords = (const float*)d_in[2];   // manifold_coords [8192,2] f32
    float* out = (float*)d_out;

    float2* lists  = (float2*)d_ws;                               // 128 KB
    int*    cnts   = (int*)((char*)d_ws + 2 * K_CL * CAP * sizeof(float));
    float*  hinges = (float*)((char*)cnts + 256);

    gather_kernel<<<K_CL, 256, 0, stream>>>(labels, coords, lists, cnts);
    dim3 grid(K_CL, K_CL);
    pair_min_kernel<<<grid, 256, 0, stream>>>(lists, cnts, hinges);
    reduce_hinge_kernel<<<1, 256, 0, stream>>>(hinges, out);
}